// Round 6
// baseline (462.136 us; speedup 1.0000x reference)
//
#include <hip/hip_runtime.h>
#include <math.h>

#define EMBED 64

__device__ __forceinline__ float dot4(float4 a, float4 b) {
    return fmaf(a.x, b.x, fmaf(a.y, b.y, fmaf(a.z, b.z, a.w * b.w)));
}

// reduce across the 16 lanes of an edge-subgroup (lane bits 0..3)
__device__ __forceinline__ float red16(float d) {
    d += __shfl_xor(d, 1);
    d += __shfl_xor(d, 2);
    d += __shfl_xor(d, 4);
    d += __shfl_xor(d, 8);
    return d;
}

// out[0] = h0 (layer-0 embedding), straight float4 copy
__global__ void copy_h0_kernel(const float* __restrict__ h0, float* __restrict__ out, int n4) {
    int i = blockIdx.x * blockDim.x + threadIdx.x;
    if (i < n4) ((float4*)out)[i] = ((const float4*)h0)[i];
}

// edge_row is sorted ascending -> build CSR row_ptr[N+1] by boundary scatter
__global__ void build_rowptr_kernel(const int* __restrict__ row, int* __restrict__ rp, int E, int N) {
    int i = blockIdx.x * blockDim.x + threadIdx.x;
    if (i >= E) return;
    if (i == 0) {
        int r0 = row[0];
        for (int r = 0; r <= r0; ++r) rp[r] = 0;
    } else {
        int a = row[i - 1], b = row[i];
        for (int r = a + 1; r <= b; ++r) rp[r] = i;
    }
    if (i == E - 1) {
        int rl = row[E - 1];
        for (int r = rl + 1; r <= N; ++r) rp[r] = E;
    }
}

// ---------------- edge-parallel logits ----------------
// Pure gather stream: 16 edges / wave / iter = 8 row-gather instructions in
// flight (4 t_att cold + 4 h_att, L1-hot since edge_row is sorted). No per-node
// phases, no LDS, no tail waste beyond one clamped final iteration.
// Lane layout: eg = lane>>4 (edge in quad), q = lane&15 (float4 slice).
__global__ void __launch_bounds__(256, 8) edge_logits_kernel(
        const float* __restrict__ ha, const float* __restrict__ ta,
        const int* __restrict__ row, const int* __restrict__ col,
        float* __restrict__ logits, int E, int totalWaves) {
    int wid = (blockIdx.x * blockDim.x + threadIdx.x) >> 6;
    int lane = threadIdx.x & 63;
    int eg = lane >> 4, q = lane & 15;
    const float4* ha4 = (const float4*)ha;
    const float4* ta4 = (const float4*)ta;

    for (int base = wid * 16; base < E; base += totalWaves * 16) {
        int j0 = base + eg, j1 = base + 4 + eg, j2 = base + 8 + eg, j3 = base + 12 + eg;
        int i0 = min(j0, E - 1), i1 = min(j1, E - 1);
        int i2 = min(j2, E - 1), i3 = min(j3, E - 1);
        int r0 = row[i0], r1 = row[i1], r2 = row[i2], r3 = row[i3];
        int c0 = col[i0], c1 = col[i1], c2 = col[i2], c3 = col[i3];
        float4 t0 = ta4[(size_t)c0 * 16 + q];
        float4 t1 = ta4[(size_t)c1 * 16 + q];
        float4 t2 = ta4[(size_t)c2 * 16 + q];
        float4 t3 = ta4[(size_t)c3 * 16 + q];
        float4 a0 = ha4[(size_t)r0 * 16 + q];
        float4 a1 = ha4[(size_t)r1 * 16 + q];
        float4 a2 = ha4[(size_t)r2 * 16 + q];
        float4 a3 = ha4[(size_t)r3 * 16 + q];
        float d0 = red16(dot4(a0, t0));
        float d1 = red16(dot4(a1, t1));
        float d2 = red16(dot4(a2, t2));
        float d3 = red16(dot4(a3, t3));
        if (q == 0) {
            if (j0 < E) logits[j0] = d0;
            if (j1 < E) logits[j1] = d1;
            if (j2 < E) logits[j2] = d2;
            if (j3 < E) logits[j3] = d3;
        }
    }
}

// one WAVE per node: softmax over CSR range, in-place logits -> weights.
__global__ void __launch_bounds__(256) node_softmax_kernel(
        const int* __restrict__ rp, float* __restrict__ lw, int N) {
    int n = (blockIdx.x * blockDim.x + threadIdx.x) >> 6;
    int lane = threadIdx.x & 63;
    if (n >= N) return;
    int s = rp[n], t = rp[n + 1];
    int deg = t - s;
    if (deg <= 0) return;

    if (deg <= 64) {
        float v = (lane < deg) ? lw[s + lane] : -1e30f;
        float m = v;
        #pragma unroll
        for (int off = 32; off > 0; off >>= 1) m = fmaxf(m, __shfl_xor(m, off));
        float e = (lane < deg) ? __expf(v - m) : 0.f;
        float sum = e;
        #pragma unroll
        for (int off = 32; off > 0; off >>= 1) sum += __shfl_xor(sum, off);
        float inv = 1.f / fmaxf(sum, 1e-12f);
        if (lane < deg) lw[s + lane] = e * inv;
    } else {
        float m = -1e30f;
        for (int e = s + lane; e < t; e += 64) m = fmaxf(m, lw[e]);
        #pragma unroll
        for (int off = 32; off > 0; off >>= 1) m = fmaxf(m, __shfl_xor(m, off));
        float sum = 0.f;
        for (int e = s + lane; e < t; e += 64) sum += __expf(lw[e] - m);
        #pragma unroll
        for (int off = 32; off > 0; off >>= 1) sum += __shfl_xor(sum, off);
        float inv = 1.f / fmaxf(sum, 1e-12f);
        for (int e = s + lane; e < t; e += 64) lw[e] = __expf(lw[e] - m) * inv;
    }
}

// ---------------- SpMM: add_out[n] = h_in[n] + sum_e w_e * h_in[col_e] ----------------
// wave = 4 edge-subgroups x 16 dim-lanes; 4 edges (1 KB) per gather instruction,
// 4 gathers (4 KB) in flight per iteration. Clamped-16 tail keeps 4 loads in
// flight even in the tail (4-edge tail steps measured SLOWER: latency-bound).
__global__ void __launch_bounds__(256, 8) spmm_kernel(
        const float* __restrict__ h_in, const int* __restrict__ col,
        const float* __restrict__ ew, const int* __restrict__ rp,
        float* __restrict__ add_out, int N, int totalWaves) {
    int wid = (blockIdx.x * blockDim.x + threadIdx.x) >> 6;
    int lane = threadIdx.x & 63;
    int eg = lane >> 4, q = lane & 15;
    const float4* h4 = (const float4*)h_in;

    for (int n = wid; n < N; n += totalWaves) {
        int s = rp[n], t = rp[n + 1];
        float4 self = h4[(size_t)n * 16 + q];
        float4 a0 = make_float4(0.f, 0.f, 0.f, 0.f);
        float4 a1 = make_float4(0.f, 0.f, 0.f, 0.f);
        int e0 = s;
        for (; e0 + 16 <= t; e0 += 16) {               // unclamped main step
            int i0 = e0 + eg, i1 = e0 + 4 + eg, i2 = e0 + 8 + eg, i3 = e0 + 12 + eg;
            int c0 = col[i0], c1 = col[i1], c2 = col[i2], c3 = col[i3];
            float w0 = ew[i0], w1 = ew[i1], w2 = ew[i2], w3 = ew[i3];
            float4 v0 = h4[(size_t)c0 * 16 + q];
            float4 v1 = h4[(size_t)c1 * 16 + q];
            float4 v2 = h4[(size_t)c2 * 16 + q];
            float4 v3 = h4[(size_t)c3 * 16 + q];
            a0.x = fmaf(w0, v0.x, a0.x); a0.y = fmaf(w0, v0.y, a0.y);
            a0.z = fmaf(w0, v0.z, a0.z); a0.w = fmaf(w0, v0.w, a0.w);
            a1.x = fmaf(w1, v1.x, a1.x); a1.y = fmaf(w1, v1.y, a1.y);
            a1.z = fmaf(w1, v1.z, a1.z); a1.w = fmaf(w1, v1.w, a1.w);
            a0.x = fmaf(w2, v2.x, a0.x); a0.y = fmaf(w2, v2.y, a0.y);
            a0.z = fmaf(w2, v2.z, a0.z); a0.w = fmaf(w2, v2.w, a0.w);
            a1.x = fmaf(w3, v3.x, a1.x); a1.y = fmaf(w3, v3.y, a1.y);
            a1.z = fmaf(w3, v3.z, a1.z); a1.w = fmaf(w3, v3.w, a1.w);
        }
        if (e0 < t) {                                  // one clamped tail step
            int j0 = e0 + eg, j1 = e0 + 4 + eg, j2 = e0 + 8 + eg, j3 = e0 + 12 + eg;
            int i0 = min(j0, t - 1), i1 = min(j1, t - 1);
            int i2 = min(j2, t - 1), i3 = min(j3, t - 1);
            int c0 = col[i0], c1 = col[i1], c2 = col[i2], c3 = col[i3];
            float w0 = (j0 < t) ? ew[i0] : 0.f;
            float w1 = (j1 < t) ? ew[i1] : 0.f;
            float w2 = (j2 < t) ? ew[i2] : 0.f;
            float w3 = (j3 < t) ? ew[i3] : 0.f;
            float4 v0 = h4[(size_t)c0 * 16 + q];
            float4 v1 = h4[(size_t)c1 * 16 + q];
            float4 v2 = h4[(size_t)c2 * 16 + q];
            float4 v3 = h4[(size_t)c3 * 16 + q];
            a0.x = fmaf(w0, v0.x, a0.x); a0.y = fmaf(w0, v0.y, a0.y);
            a0.z = fmaf(w0, v0.z, a0.z); a0.w = fmaf(w0, v0.w, a0.w);
            a1.x = fmaf(w1, v1.x, a1.x); a1.y = fmaf(w1, v1.y, a1.y);
            a1.z = fmaf(w1, v1.z, a1.z); a1.w = fmaf(w1, v1.w, a1.w);
            a0.x = fmaf(w2, v2.x, a0.x); a0.y = fmaf(w2, v2.y, a0.y);
            a0.z = fmaf(w2, v2.z, a0.z); a0.w = fmaf(w2, v2.w, a0.w);
            a1.x = fmaf(w3, v3.x, a1.x); a1.y = fmaf(w3, v3.y, a1.y);
            a1.z = fmaf(w3, v3.z, a1.z); a1.w = fmaf(w3, v3.w, a1.w);
        }
        a0.x += a1.x; a0.y += a1.y; a0.z += a1.z; a0.w += a1.w;
        // reduce across the 4 edge-subgroups (lane bits 4,5)
        a0.x += __shfl_xor(a0.x, 16); a0.y += __shfl_xor(a0.y, 16);
        a0.z += __shfl_xor(a0.z, 16); a0.w += __shfl_xor(a0.w, 16);
        a0.x += __shfl_xor(a0.x, 32); a0.y += __shfl_xor(a0.y, 32);
        a0.z += __shfl_xor(a0.z, 32); a0.w += __shfl_xor(a0.w, 32);
        if (eg == 0) {
            float4 r;
            r.x = self.x + a0.x; r.y = self.y + a0.y;
            r.z = self.z + a0.z; r.w = self.w + a0.w;
            ((float4*)add_out)[(size_t)n * 16 + q] = r;
        }
    }
}

// ---------------- dense epilogue: x = relu(add @ W^T + b); out = x/max(||x||,eps) ----------------
// LDS row-broadcast matmul: stage node row once (1 ds_write_b32), read back as
// 16 uniform-address ds_read_b128 broadcasts; 4 independent fma chains;
// next row prefetched during compute. W in 64 VGPRs -> (256,4), grid 1024.
__global__ void __launch_bounds__(256, 4) dense_kernel(
        const float* __restrict__ W, const float* __restrict__ b,
        float* __restrict__ io, int N, int totalWaves) {
    __shared__ float4 rbuf[4][17];          // one 64-float row per wave slot
    int wid = (blockIdx.x * blockDim.x + threadIdx.x) >> 6;
    int lane = threadIdx.x & 63;
    int ws = threadIdx.x >> 6;

    float4 Wr[16];
    const float4* W4 = (const float4*)W;
    #pragma unroll
    for (int p = 0; p < 16; ++p) Wr[p] = W4[lane * 16 + p];
    float bias = b[lane];
    float* rb = (float*)&rbuf[ws][0];

    float vcur = 0.f;
    if (wid < N) vcur = io[(size_t)wid * EMBED + lane];

    for (int n = wid; n < N; n += totalWaves) {
        rb[lane] = vcur;                    // stage current row (coalesced, 2/bank = free)
        int n2 = n + totalWaves;
        float vnext = 0.f;
        if (n2 < N) vnext = io[(size_t)n2 * EMBED + lane];  // prefetch next row

        float x0 = bias, x1 = 0.f, x2 = 0.f, x3 = 0.f;
        #pragma unroll
        for (int j = 0; j < 4; ++j) {
            float4 a0 = rbuf[ws][4 * j + 0];    // uniform addr -> broadcast, no conflict
            float4 a1 = rbuf[ws][4 * j + 1];
            float4 a2 = rbuf[ws][4 * j + 2];
            float4 a3 = rbuf[ws][4 * j + 3];
            float4 w0 = Wr[4 * j + 0], w1 = Wr[4 * j + 1];
            float4 w2 = Wr[4 * j + 2], w3 = Wr[4 * j + 3];
            x0 = fmaf(a0.x, w0.x, x0); x0 = fmaf(a0.y, w0.y, x0);
            x0 = fmaf(a0.z, w0.z, x0); x0 = fmaf(a0.w, w0.w, x0);
            x1 = fmaf(a1.x, w1.x, x1); x1 = fmaf(a1.y, w1.y, x1);
            x1 = fmaf(a1.z, w1.z, x1); x1 = fmaf(a1.w, w1.w, x1);
            x2 = fmaf(a2.x, w2.x, x2); x2 = fmaf(a2.y, w2.y, x2);
            x2 = fmaf(a2.z, w2.z, x2); x2 = fmaf(a2.w, w2.w, x2);
            x3 = fmaf(a3.x, w3.x, x3); x3 = fmaf(a3.y, w3.y, x3);
            x3 = fmaf(a3.z, w3.z, x3); x3 = fmaf(a3.w, w3.w, x3);
        }
        float x = fmaxf((x0 + x1) + (x2 + x3), 0.f);

        float ss = x * x;
        #pragma unroll
        for (int off = 32; off > 0; off >>= 1) ss += __shfl_xor(ss, off);
        float scale = 1.f / fmaxf(sqrtf(ss), 1e-12f);
        io[(size_t)n * EMBED + lane] = x * scale;
        vcur = vnext;
    }
}

extern "C" void kernel_launch(void* const* d_in, const int* in_sizes, int n_in,
                              void* d_out, int out_size, void* d_ws, size_t ws_size,
                              hipStream_t stream) {
    const float* h0   = (const float*)d_in[0];
    const float* ha   = (const float*)d_in[1];
    const float* ta   = (const float*)d_in[2];
    const float* w1   = (const float*)d_in[3];
    const float* b1   = (const float*)d_in[4];
    const float* w2   = (const float*)d_in[5];
    const float* b2   = (const float*)d_in[6];
    const int*   erow = (const int*)d_in[7];
    const int*   ecol = (const int*)d_in[8];

    const int N = in_sizes[0] / EMBED;
    const int E = in_sizes[7];
    float* out = (float*)d_out;

    // workspace: row_ptr[N+1] ints, then edge weights[E] floats
    int*   rp = (int*)d_ws;
    size_t rp_bytes = ((size_t)(N + 1) * sizeof(int) + 255) & ~(size_t)255;
    float* ew = (float*)((char*)d_ws + rp_bytes);

    // 1. out[0] = h0
    {
        int n4 = N * EMBED / 4;
        copy_h0_kernel<<<(n4 + 255) / 256, 256, 0, stream>>>(h0, out, n4);
    }
    // 2. CSR row_ptr
    build_rowptr_kernel<<<(E + 255) / 256, 256, 0, stream>>>(erow, rp, E, N);
    // 3. edge-parallel logits (pure gather stream)
    edge_logits_kernel<<<2048, 256, 0, stream>>>(ha, ta, erow, ecol, ew, E, 2048 * 4);
    // 4. per-node softmax (one wave/node, in-place logits -> weights)
    {
        int waves_per_block = 256 / 64;
        int blocks = (N + waves_per_block - 1) / waves_per_block;
        node_softmax_kernel<<<blocks, 256, 0, stream>>>(rp, ew, N);
    }

    // 5. layer 1: spmm(h0 -> out1-as-add), dense in place; layer 2 likewise
    float* out1 = out + (size_t)N * EMBED;
    float* out2 = out + 2 * (size_t)N * EMBED;
    spmm_kernel<<<2048, 256, 0, stream>>>(h0, ecol, ew, rp, out1, N, 2048 * 4);
    dense_kernel<<<1024, 256, 0, stream>>>(w1, b1, out1, N, 1024 * 4);
    spmm_kernel<<<2048, 256, 0, stream>>>(out1, ecol, ew, rp, out2, N, 2048 * 4);
    dense_kernel<<<1024, 256, 0, stream>>>(w2, b2, out2, N, 1024 * 4);
}

// Round 7
// 417.291 us; speedup vs baseline: 1.1075x; 1.1075x over previous
//
#include <hip/hip_runtime.h>
#include <math.h>

#define EMBED 64

__device__ __forceinline__ float dot4(float4 a, float4 b) {
    return fmaf(a.x, b.x, fmaf(a.y, b.y, fmaf(a.z, b.z, a.w * b.w)));
}

// reduce across the 16 lanes of an edge-subgroup (lane bits 0..3)
__device__ __forceinline__ float red16(float d) {
    d += __shfl_xor(d, 1);
    d += __shfl_xor(d, 2);
    d += __shfl_xor(d, 4);
    d += __shfl_xor(d, 8);
    return d;
}

// ---------------- K1: CSR rowptr build + edge-parallel logits (independent phases) ----------------
__global__ void __launch_bounds__(256, 8) rowptr_logits_kernel(
        const float* __restrict__ ha, const float* __restrict__ ta,
        const int* __restrict__ row, const int* __restrict__ col,
        int* __restrict__ rp, float* __restrict__ logits,
        int E, int N, int totalThreads, int totalWaves) {
    int tid = blockIdx.x * blockDim.x + threadIdx.x;

    // phase A: rowptr boundary scatter (thread per edge, grid-stride)
    for (int i = tid; i < E; i += totalThreads) {
        if (i == 0) {
            int r0 = row[0];
            for (int r = 0; r <= r0; ++r) rp[r] = 0;
        } else {
            int a = row[i - 1], b = row[i];
            for (int r = a + 1; r <= b; ++r) rp[r] = i;
        }
        if (i == E - 1) {
            int rl = row[E - 1];
            for (int r = rl + 1; r <= N; ++r) rp[r] = E;
        }
    }

    // phase B: logits, 16 edges/wave/iter = 8 row-gathers in flight
    int wid = tid >> 6;
    int lane = threadIdx.x & 63;
    int eg = lane >> 4, q = lane & 15;
    const float4* ha4 = (const float4*)ha;
    const float4* ta4 = (const float4*)ta;

    for (int base = wid * 16; base < E; base += totalWaves * 16) {
        int j0 = base + eg, j1 = base + 4 + eg, j2 = base + 8 + eg, j3 = base + 12 + eg;
        int i0 = min(j0, E - 1), i1 = min(j1, E - 1);
        int i2 = min(j2, E - 1), i3 = min(j3, E - 1);
        int r0 = row[i0], r1 = row[i1], r2 = row[i2], r3 = row[i3];
        int c0 = col[i0], c1 = col[i1], c2 = col[i2], c3 = col[i3];
        float4 t0 = ta4[(size_t)c0 * 16 + q];
        float4 t1 = ta4[(size_t)c1 * 16 + q];
        float4 t2 = ta4[(size_t)c2 * 16 + q];
        float4 t3 = ta4[(size_t)c3 * 16 + q];
        float4 a0 = ha4[(size_t)r0 * 16 + q];
        float4 a1 = ha4[(size_t)r1 * 16 + q];
        float4 a2 = ha4[(size_t)r2 * 16 + q];
        float4 a3 = ha4[(size_t)r3 * 16 + q];
        float d0 = red16(dot4(a0, t0));
        float d1 = red16(dot4(a1, t1));
        float d2 = red16(dot4(a2, t2));
        float d3 = red16(dot4(a3, t3));
        if (q == 0) {
            if (j0 < E) logits[j0] = d0;
            if (j1 < E) logits[j1] = d1;
            if (j2 < E) logits[j2] = d2;
            if (j3 < E) logits[j3] = d3;
        }
    }
}

// ---------------- K2: out[0]=h0 copy + per-node softmax (grid-stride both) ----------------
__global__ void __launch_bounds__(256) copy_softmax_kernel(
        const float* __restrict__ h0, float* __restrict__ out0, int n4,
        const int* __restrict__ rp, float* __restrict__ lw, int N,
        int totalThreads, int totalWaves) {
    int tid = blockIdx.x * blockDim.x + threadIdx.x;
    // phase A: float4 copy
    for (int i = tid; i < n4; i += totalThreads)
        ((float4*)out0)[i] = ((const float4*)h0)[i];

    // phase B: wave-per-node softmax, in-place logits -> weights
    int wid = tid >> 6;
    int lane = threadIdx.x & 63;
    for (int n = wid; n < N; n += totalWaves) {
        int s = rp[n], t = rp[n + 1];
        int deg = t - s;
        if (deg <= 0) continue;
        if (deg <= 64) {
            float v = (lane < deg) ? lw[s + lane] : -1e30f;
            float m = v;
            #pragma unroll
            for (int off = 32; off > 0; off >>= 1) m = fmaxf(m, __shfl_xor(m, off));
            float e = (lane < deg) ? __expf(v - m) : 0.f;
            float sum = e;
            #pragma unroll
            for (int off = 32; off > 0; off >>= 1) sum += __shfl_xor(sum, off);
            float inv = 1.f / fmaxf(sum, 1e-12f);
            if (lane < deg) lw[s + lane] = e * inv;
        } else {
            float m = -1e30f;
            for (int e = s + lane; e < t; e += 64) m = fmaxf(m, lw[e]);
            #pragma unroll
            for (int off = 32; off > 0; off >>= 1) m = fmaxf(m, __shfl_xor(m, off));
            float sum = 0.f;
            for (int e = s + lane; e < t; e += 64) sum += __expf(lw[e] - m);
            #pragma unroll
            for (int off = 32; off > 0; off >>= 1) sum += __shfl_xor(sum, off);
            float inv = 1.f / fmaxf(sum, 1e-12f);
            for (int e = s + lane; e < t; e += 64) lw[e] = __expf(lw[e] - m) * inv;
        }
    }
}

// ---------------- K3/K4: fused prop layer: spmm gather + LDS-broadcast dense + norm ----------------
// spmm: wave = 4 edge-subgroups x 16 dim-lanes, 4 edges (1 KB) per gather instr,
// clamped-16 tail (keeps 4 loads in flight; 4-edge tails measured slower).
// dense: xor-butterfly leaves full add-row replicated in all lanes' q-slices;
// stage once to LDS (1 ds_write_b128 by 16 lanes), 16 uniform ds_read_b128
// broadcasts, 4 independent fma chains. Dense VALU/DS hides under other waves'
// gather latency. W in 64 VGPRs -> ~110 VGPR, (256,4), grid 1024 resident.
__global__ void __launch_bounds__(256, 4) prop_layer_kernel(
        const float* __restrict__ h_in,
        const float* __restrict__ W, const float* __restrict__ b,
        const int* __restrict__ col, const float* __restrict__ ew,
        const int* __restrict__ rp,
        float* __restrict__ out, int N, int totalWaves) {
    __shared__ float4 rbuf[4][17];
    int wid = (blockIdx.x * blockDim.x + threadIdx.x) >> 6;
    int lane = threadIdx.x & 63;
    int ws = threadIdx.x >> 6;
    int eg = lane >> 4, q = lane & 15;
    const float4* h4 = (const float4*)h_in;

    float4 Wr[16];
    const float4* W4 = (const float4*)W;
    #pragma unroll
    for (int p = 0; p < 16; ++p) Wr[p] = W4[lane * 16 + p];
    float bias = b[lane];

    for (int n = wid; n < N; n += totalWaves) {
        int s = rp[n], t = rp[n + 1];
        float4 self = h4[(size_t)n * 16 + q];
        float4 a0 = make_float4(0.f, 0.f, 0.f, 0.f);
        float4 a1 = make_float4(0.f, 0.f, 0.f, 0.f);
        int e0 = s;
        for (; e0 + 16 <= t; e0 += 16) {               // unclamped main step
            int i0 = e0 + eg, i1 = e0 + 4 + eg, i2 = e0 + 8 + eg, i3 = e0 + 12 + eg;
            int c0 = col[i0], c1 = col[i1], c2 = col[i2], c3 = col[i3];
            float w0 = ew[i0], w1 = ew[i1], w2 = ew[i2], w3 = ew[i3];
            float4 v0 = h4[(size_t)c0 * 16 + q];
            float4 v1 = h4[(size_t)c1 * 16 + q];
            float4 v2 = h4[(size_t)c2 * 16 + q];
            float4 v3 = h4[(size_t)c3 * 16 + q];
            a0.x = fmaf(w0, v0.x, a0.x); a0.y = fmaf(w0, v0.y, a0.y);
            a0.z = fmaf(w0, v0.z, a0.z); a0.w = fmaf(w0, v0.w, a0.w);
            a1.x = fmaf(w1, v1.x, a1.x); a1.y = fmaf(w1, v1.y, a1.y);
            a1.z = fmaf(w1, v1.z, a1.z); a1.w = fmaf(w1, v1.w, a1.w);
            a0.x = fmaf(w2, v2.x, a0.x); a0.y = fmaf(w2, v2.y, a0.y);
            a0.z = fmaf(w2, v2.z, a0.z); a0.w = fmaf(w2, v2.w, a0.w);
            a1.x = fmaf(w3, v3.x, a1.x); a1.y = fmaf(w3, v3.y, a1.y);
            a1.z = fmaf(w3, v3.z, a1.z); a1.w = fmaf(w3, v3.w, a1.w);
        }
        if (e0 < t) {                                  // one clamped tail step
            int j0 = e0 + eg, j1 = e0 + 4 + eg, j2 = e0 + 8 + eg, j3 = e0 + 12 + eg;
            int i0 = min(j0, t - 1), i1 = min(j1, t - 1);
            int i2 = min(j2, t - 1), i3 = min(j3, t - 1);
            int c0 = col[i0], c1 = col[i1], c2 = col[i2], c3 = col[i3];
            float w0 = (j0 < t) ? ew[i0] : 0.f;
            float w1 = (j1 < t) ? ew[i1] : 0.f;
            float w2 = (j2 < t) ? ew[i2] : 0.f;
            float w3 = (j3 < t) ? ew[i3] : 0.f;
            float4 v0 = h4[(size_t)c0 * 16 + q];
            float4 v1 = h4[(size_t)c1 * 16 + q];
            float4 v2 = h4[(size_t)c2 * 16 + q];
            float4 v3 = h4[(size_t)c3 * 16 + q];
            a0.x = fmaf(w0, v0.x, a0.x); a0.y = fmaf(w0, v0.y, a0.y);
            a0.z = fmaf(w0, v0.z, a0.z); a0.w = fmaf(w0, v0.w, a0.w);
            a1.x = fmaf(w1, v1.x, a1.x); a1.y = fmaf(w1, v1.y, a1.y);
            a1.z = fmaf(w1, v1.z, a1.z); a1.w = fmaf(w1, v1.w, a1.w);
            a0.x = fmaf(w2, v2.x, a0.x); a0.y = fmaf(w2, v2.y, a0.y);
            a0.z = fmaf(w2, v2.z, a0.z); a0.w = fmaf(w2, v2.w, a0.w);
            a1.x = fmaf(w3, v3.x, a1.x); a1.y = fmaf(w3, v3.y, a1.y);
            a1.z = fmaf(w3, v3.z, a1.z); a1.w = fmaf(w3, v3.w, a1.w);
        }
        a0.x += a1.x; a0.y += a1.y; a0.z += a1.z; a0.w += a1.w;
        // xor-butterfly over lane bits 4,5: ALL lanes end with the subgroup total
        a0.x += __shfl_xor(a0.x, 16); a0.y += __shfl_xor(a0.y, 16);
        a0.z += __shfl_xor(a0.z, 16); a0.w += __shfl_xor(a0.w, 16);
        a0.x += __shfl_xor(a0.x, 32); a0.y += __shfl_xor(a0.y, 32);
        a0.z += __shfl_xor(a0.z, 32); a0.w += __shfl_xor(a0.w, 32);

        // stage add-row to LDS (lanes 0-15 cover the 64 floats)
        if (eg == 0) {
            float4 r;
            r.x = self.x + a0.x; r.y = self.y + a0.y;
            r.z = self.z + a0.z; r.w = self.w + a0.w;
            rbuf[ws][q] = r;
        }
        asm volatile("s_waitcnt lgkmcnt(0)" ::: "memory");  // wave-synchronous

        // dense: x[lane] = relu(add . W[lane] + b[lane]), then L2-normalize
        float x0 = bias, x1 = 0.f, x2 = 0.f, x3 = 0.f;
        #pragma unroll
        for (int j = 0; j < 4; ++j) {
            float4 b0 = rbuf[ws][4 * j + 0];    // uniform addr -> broadcast
            float4 b1 = rbuf[ws][4 * j + 1];
            float4 b2 = rbuf[ws][4 * j + 2];
            float4 b3 = rbuf[ws][4 * j + 3];
            float4 w0 = Wr[4 * j + 0], w1 = Wr[4 * j + 1];
            float4 w2 = Wr[4 * j + 2], w3 = Wr[4 * j + 3];
            x0 = fmaf(b0.x, w0.x, x0); x0 = fmaf(b0.y, w0.y, x0);
            x0 = fmaf(b0.z, w0.z, x0); x0 = fmaf(b0.w, w0.w, x0);
            x1 = fmaf(b1.x, w1.x, x1); x1 = fmaf(b1.y, w1.y, x1);
            x1 = fmaf(b1.z, w1.z, x1); x1 = fmaf(b1.w, w1.w, x1);
            x2 = fmaf(b2.x, w2.x, x2); x2 = fmaf(b2.y, w2.y, x2);
            x2 = fmaf(b2.z, w2.z, x2); x2 = fmaf(b2.w, w2.w, x2);
            x3 = fmaf(b3.x, w3.x, x3); x3 = fmaf(b3.y, w3.y, x3);
            x3 = fmaf(b3.z, w3.z, x3); x3 = fmaf(b3.w, w3.w, x3);
        }
        float x = fmaxf((x0 + x1) + (x2 + x3), 0.f);

        float ss = x * x;
        #pragma unroll
        for (int off = 32; off > 0; off >>= 1) ss += __shfl_xor(ss, off);
        float scale = 1.f / fmaxf(sqrtf(ss), 1e-12f);
        out[(size_t)n * EMBED + lane] = x * scale;
    }
}

extern "C" void kernel_launch(void* const* d_in, const int* in_sizes, int n_in,
                              void* d_out, int out_size, void* d_ws, size_t ws_size,
                              hipStream_t stream) {
    const float* h0   = (const float*)d_in[0];
    const float* ha   = (const float*)d_in[1];
    const float* ta   = (const float*)d_in[2];
    const float* w1   = (const float*)d_in[3];
    const float* b1   = (const float*)d_in[4];
    const float* w2   = (const float*)d_in[5];
    const float* b2   = (const float*)d_in[6];
    const int*   erow = (const int*)d_in[7];
    const int*   ecol = (const int*)d_in[8];

    const int N = in_sizes[0] / EMBED;
    const int E = in_sizes[7];
    float* out = (float*)d_out;

    // workspace: row_ptr[N+1] ints, then edge weights[E] floats
    int*   rp = (int*)d_ws;
    size_t rp_bytes = ((size_t)(N + 1) * sizeof(int) + 255) & ~(size_t)255;
    float* ew = (float*)((char*)d_ws + rp_bytes);

    // K1: rowptr + logits (independent phases, one launch)
    rowptr_logits_kernel<<<2048, 256, 0, stream>>>(
        ha, ta, erow, ecol, rp, ew, E, N, 2048 * 256, 2048 * 4);

    // K2: out[0] = h0 copy + per-node softmax
    copy_softmax_kernel<<<2048, 256, 0, stream>>>(
        h0, out, N * EMBED / 4, rp, ew, N, 2048 * 256, 2048 * 4);

    // K3/K4: fused prop layers
    float* out1 = out + (size_t)N * EMBED;
    float* out2 = out + 2 * (size_t)N * EMBED;
    prop_layer_kernel<<<1024, 256, 0, stream>>>(h0,   w1, b1, ecol, ew, rp, out1, N, 1024 * 4);
    prop_layer_kernel<<<1024, 256, 0, stream>>>(out1, w2, b2, ecol, ew, rp, out2, N, 1024 * 4);
}